// Round 2
// baseline (834.022 us; speedup 1.0000x reference)
//
#include <hip/hip_runtime.h>
#include <cstdint>
#include <cstddef>

// Problem constants (B, N, C) = (4, 6144, 256), M = 3, n = 2048
#define B_   4
#define N_   6144
#define C_   256
#define M_   3
#define NLOC 2048
#define R_T  32     // rows per fused block

static_assert(N_ == M_ * NLOC, "shape");

typedef __bf16 bf16;
typedef __bf16 bf16x4 __attribute__((ext_vector_type(4)));  // 8B
typedef __bf16 bf16x8 __attribute__((ext_vector_type(8)));  // MFMA A/B operand
typedef float  f32x4  __attribute__((ext_vector_type(4)));  // 16B chunk

// lgkm-only barrier: LDS writes become visible WITHOUT draining outstanding
// global prefetch loads (__syncthreads() emits s_waitcnt vmcnt(0)).
#define BARRIER_LGKM() asm volatile("s_waitcnt lgkmcnt(0)\n\ts_barrier" ::: "memory")

// ---------------------------------------------------------------------------
// One dispatch for all three transposes (x, W_feat, W_raw), fp32 -> bf16:
//   job 0: x  (B slices, N x C)  -> xT  (B, C, N)   blocks [0, 6144)
//   job 1: Wf (M slices, C x C)  -> WfT (M, C, C)   blocks [6144, 6336)
//   job 2: Wr (M slices, C x C)  -> WrT (M, C, C)   blocks [6336, 6528)
// ---------------------------------------------------------------------------
__global__ void transpose_all_k(const float* __restrict__ x,
                                const float* __restrict__ Wf,
                                const float* __restrict__ Wr,
                                bf16* __restrict__ xT,
                                bf16* __restrict__ WfT,
                                bf16* __restrict__ WrT) {
    const int id = blockIdx.x;
    const float* src;
    bf16* dst;
    int R, rb, cb;
    if (id < 6144) {                       // x: 4 slices x (192 rowblk x 8 colblk)
        const int s = id / 1536, r = id % 1536;
        rb = (r >> 3) * 32; cb = (r & 7) * 32;
        src = x  + (size_t)s * N_ * C_;
        dst = xT + (size_t)s * N_ * C_;
        R = N_;
    } else {                               // W: 2 mats x 3 slices x 64 blocks
        const int id2 = id - 6144;
        const int mat = id2 / 192, r = id2 % 192;
        const int s = r / 64, r2 = r % 64;
        rb = (r2 >> 3) * 32; cb = (r2 & 7) * 32;
        src = (mat ? Wr : Wf) + (size_t)s * C_ * C_;
        dst = (mat ? WrT : WfT) + (size_t)s * C_ * C_;
        R = C_;
    }
    __shared__ bf16 tile[32][33];
    const int tx = threadIdx.x, ty = threadIdx.y;  // 32 x 8
#pragma unroll
    for (int k = 0; k < 4; ++k)
        tile[ty + 8 * k][tx] = (bf16)src[(size_t)(rb + ty + 8 * k) * C_ + (cb + tx)];
    __syncthreads();
#pragma unroll
    for (int k = 0; k < 4; ++k)
        dst[(size_t)(cb + ty + 8 * k) * R + (rb + tx)] = tile[tx][ty + 8 * k];
}

// ---------------------------------------------------------------------------
// Fully fused kernel: per (b, modal i, 32-row tile):
//  phase 1: aggr_pre = rowL1norm(e_masked) @ x        (K = 2048, bf16 MFMA)
//  phase 2: feat = x@Wf + bf; ag = aggr_pre@Wr + br   (K = 256 each)
//  epilogue: beta = sigmoid(...); h = lerp; out = relu(LN(h))
// aggr_pre never touches global memory (acc -> LDS Pg -> MFMA A-operand).
// Grid (64, 3, 4) = 768 blocks = exactly 3/CU. LDS union = 39 KB.
// ---------------------------------------------------------------------------
struct P1 {
    bf16  Abuf[2][4][R_T][8];    // [buf][k-chunk][row][8]      4 KB
    bf16  Bbuf[2][4][256][8];    // [buf][k-chunk][col][8]     32 KB
    float rsum[R_T][8];          //                             1 KB
};
struct P2 {
    bf16  Pg[32][R_T][8];        // aggr_pre bf16 [k-chunk][row][8]  16 KB
    bf16  Bw[4][256][8];         // weight k-step stage              16 KB
    float prm[6][256];           // bf,br,wA,wB,gamma,beta            6 KB
    float red[3][2][R_T];        // cross-wave row reductions
    float rinv[R_T];             // 1/L1 per row
};
union FusedLds { P1 p1; P2 p2; };

__global__ __launch_bounds__(256) void fused_k(
    const float* __restrict__ e,       // (B, N, N) fp32
    const float* __restrict__ x,       // (B, N, C) fp32
    const bf16*  __restrict__ xT,      // (B, C, N) bf16 ws
    const bf16*  __restrict__ WfT,     // (M, C, C) bf16 ws [out][k]
    const bf16*  __restrict__ WrT,     // (M, C, C) bf16 ws [out][k]
    const float* __restrict__ b_feat, const float* __restrict__ b_raw,
    const float* __restrict__ W_beta, const float* __restrict__ b_beta,
    const float* __restrict__ ln_g,   const float* __restrict__ ln_b,
    float* __restrict__ out)           // (B, N, C) fp32
{
    __shared__ FusedLds u;

    const int rt = blockIdx.x, i = blockIdx.y, b = blockIdx.z;
    const int t = threadIdx.x;
    const int w = t >> 6, lane = t & 63, l15 = lane & 15, quad = lane >> 4;
    const int R0 = rt * R_T;

    // ======================= phase 1: aggr GEMM ===========================
    const int ar  = t >> 3;            // staged row 0..31
    const int ac4 = (t & 7) * 4;       // k-offset within 32 (4 floats)
    const int bc  = t >> 2;            // staged col base 0..63
    const int bch8 = (t & 3) * 8;      // k-offset within 32 (8 bf16)
    const int dconst = R0 + ar - ac4;  // diag col - k-offset

    const float* eptr = e + ((size_t)(b * N_ + i * NLOC + R0 + ar)) * N_
                          + i * NLOC + ac4;
    const bf16* xTb = xT + ((size_t)(b * C_ + bc)) * N_ + i * NLOC + bch8;

    f32x4 acc[2][4];
#pragma unroll
    for (int mt = 0; mt < 2; ++mt)
#pragma unroll
        for (int nt = 0; nt < 4; ++nt) { f32x4 z = {0.f, 0.f, 0.f, 0.f}; acc[mt][nt] = z; }
    float psum = 0.f;

    f32x4 eA, xA0, xA1, xA2, xA3;
    f32x4 eB, xB0, xB1, xB2, xB3;

#define AG_LOAD(EV, X0, X1, X2, X3, KK)                                          \
    do {                                                                         \
        EV = *(const f32x4*)(const void*)(eptr + (KK));                          \
        X0 = *(const f32x4*)(const void*)(xTb + (size_t)0   * N_ + (KK));        \
        X1 = *(const f32x4*)(const void*)(xTb + (size_t)64  * N_ + (KK));        \
        X2 = *(const f32x4*)(const void*)(xTb + (size_t)128 * N_ + (KK));        \
        X3 = *(const f32x4*)(const void*)(xTb + (size_t)192 * N_ + (KK));        \
    } while (0)

#define AG_STAGE(EV, X0, X1, X2, X3, KK, BUF)                                    \
    do {                                                                         \
        const int d = dconst - (KK);                                             \
        bf16x4 a4;                                                               \
        _Pragma("unroll")                                                        \
        for (int j = 0; j < 4; ++j) {                                            \
            float v = (EV)[j];                                                   \
            v = (d == j) ? 0.f : v;                                              \
            const bf16 hh = (bf16)v;                                             \
            a4[j] = hh;                                                          \
            psum += fabsf((float)hh);                                            \
        }                                                                        \
        *(bf16x4*)(void*)&u.p1.Abuf[BUF][ac4 >> 3][ar][ac4 & 7] = a4;            \
        *(f32x4*)(void*)&u.p1.Bbuf[BUF][t & 3][bc      ][0] = X0;                \
        *(f32x4*)(void*)&u.p1.Bbuf[BUF][t & 3][bc +  64][0] = X1;                \
        *(f32x4*)(void*)&u.p1.Bbuf[BUF][t & 3][bc + 128][0] = X2;                \
        *(f32x4*)(void*)&u.p1.Bbuf[BUF][t & 3][bc + 192][0] = X3;                \
    } while (0)

#define AG_COMPUTE(BUF)                                                          \
    do {                                                                         \
        const bf16x8 af0 = *(const bf16x8*)(const void*)&u.p1.Abuf[BUF][quad][l15][0];      \
        const bf16x8 af1 = *(const bf16x8*)(const void*)&u.p1.Abuf[BUF][quad][16 + l15][0]; \
        _Pragma("unroll")                                                        \
        for (int nt = 0; nt < 4; ++nt) {                                         \
            const bf16x8 bv = *(const bf16x8*)(const void*)                      \
                &u.p1.Bbuf[BUF][quad][w * 64 + nt * 16 + l15][0];                \
            acc[0][nt] = __builtin_amdgcn_mfma_f32_16x16x32_bf16(af0, bv, acc[0][nt], 0, 0, 0); \
            acc[1][nt] = __builtin_amdgcn_mfma_f32_16x16x32_bf16(af1, bv, acc[1][nt], 0, 0, 0); \
        }                                                                        \
    } while (0)

    AG_LOAD(eA, xA0, xA1, xA2, xA3, 0);
#pragma unroll 1
    for (int kk = 0; kk < NLOC; kk += 64) {
        AG_LOAD(eB, xB0, xB1, xB2, xB3, kk + 32);           // in flight across barrier
        AG_STAGE(eA, xA0, xA1, xA2, xA3, kk, 0);
        BARRIER_LGKM();
        if (kk + 64 < NLOC) AG_LOAD(eA, xA0, xA1, xA2, xA3, kk + 64);  // 2 phases ahead
        AG_COMPUTE(0);
        AG_STAGE(eB, xB0, xB1, xB2, xB3, kk + 32, 1);
        BARRIER_LGKM();
        AG_COMPUTE(1);
    }
#undef AG_LOAD
#undef AG_STAGE
#undef AG_COMPUTE

    // ---- L1 row sums -> rinv; params -> LDS; aggr_pre -> Pg (bf16) ----
    u.p1.rsum[ar][t & 7] = psum;
    __syncthreads();
    float rs = 0.f;
    if (t < R_T) {
#pragma unroll
        for (int j = 0; j < 8; ++j) rs += u.p1.rsum[t][j];
    }
    __syncthreads();   // all rsum reads done; p2 region may now be written
    if (t < R_T) u.p2.rinv[t] = 1.f / fmaxf(rs, 1e-12f);
    {
        const int c = t;
        const float w3 = W_beta[i * 768 + 512 + c];
        u.p2.prm[0][c] = b_feat[i * C_ + c];
        u.p2.prm[1][c] = b_raw[i * C_ + c];
        u.p2.prm[2][c] = W_beta[i * 768 + c] + w3;
        u.p2.prm[3][c] = W_beta[i * 768 + 256 + c] - w3;
        u.p2.prm[4][c] = ln_g[i * C_ + c];
        u.p2.prm[5][c] = ln_b[i * C_ + c];
    }
    __syncthreads();   // rinv + prm visible
#pragma unroll
    for (int mt = 0; mt < 2; ++mt) {
#pragma unroll
        for (int reg = 0; reg < 4; ++reg) {
            const int r = mt * 16 + quad * 4 + reg;
            const float iv = u.p2.rinv[r];
#pragma unroll
            for (int nt = 0; nt < 4; ++nt) {
                const int c = w * 64 + nt * 16 + l15;
                u.p2.Pg[c >> 3][r][c & 7] = (bf16)(acc[mt][nt][reg] * iv);
            }
        }
    }
    __syncthreads();   // Pg visible

    // ======================= phase 2: node GEMMs ==========================
    const int rg = w & 1, cg = w >> 1;         // row group / col half per wave
    const int wo = t >> 2;                     // staged out-channel base 0..63
    const int wch8 = (t & 3) * 8;

    const float* xrowp = x + ((size_t)(b * N_ + i * NLOC + R0 + rg * 16 + l15)) * C_ + quad * 8;
    const bf16* wfp = WfT + ((size_t)(i * C_ + wo)) * C_ + wch8;
    const bf16* wrp = WrT + ((size_t)(i * C_ + wo)) * C_ + wch8;

    f32x4 accf[8], accg[8];
#pragma unroll
    for (int nt = 0; nt < 8; ++nt) { f32x4 z = {0.f, 0.f, 0.f, 0.f}; accf[nt] = z; accg[nt] = z; }

    f32x4 wv0, wv1, wv2, wv3, xv0, xv1;

#define NF_LOADW(P, KK)                                                          \
    do {                                                                         \
        wv0 = *(const f32x4*)(const void*)((P) + (size_t)0   * C_ + (KK));       \
        wv1 = *(const f32x4*)(const void*)((P) + (size_t)64  * C_ + (KK));       \
        wv2 = *(const f32x4*)(const void*)((P) + (size_t)128 * C_ + (KK));       \
        wv3 = *(const f32x4*)(const void*)((P) + (size_t)192 * C_ + (KK));       \
    } while (0)

#define NF_STOREW()                                                              \
    do {                                                                         \
        *(f32x4*)(void*)&u.p2.Bw[t & 3][wo      ][0] = wv0;                      \
        *(f32x4*)(void*)&u.p2.Bw[t & 3][wo +  64][0] = wv1;                      \
        *(f32x4*)(void*)&u.p2.Bw[t & 3][wo + 128][0] = wv2;                      \
        *(f32x4*)(void*)&u.p2.Bw[t & 3][wo + 192][0] = wv3;                      \
    } while (0)

    // ---- feat GEMM: A = bf16(x rows) direct from global, B = WfT ----
    NF_LOADW(wfp, 0);
    xv0 = *(const f32x4*)(const void*)(xrowp);
    xv1 = *(const f32x4*)(const void*)(xrowp + 4);
#pragma unroll 1
    for (int kk = 0; kk < C_; kk += 32) {
        BARRIER_LGKM();          // prior step's Bw reads drained
        NF_STOREW();
        bf16x8 ax;
#pragma unroll
        for (int j = 0; j < 4; ++j) { ax[j] = (bf16)xv0[j]; ax[j + 4] = (bf16)xv1[j]; }
        if (kk + 32 < C_) {
            NF_LOADW(wfp, kk + 32);
            xv0 = *(const f32x4*)(const void*)(xrowp + kk + 32);
            xv1 = *(const f32x4*)(const void*)(xrowp + kk + 36);
        }
        BARRIER_LGKM();          // Bw writes visible
#pragma unroll
        for (int nt = 0; nt < 8; ++nt) {
            const bf16x8 bv = *(const bf16x8*)(const void*)
                &u.p2.Bw[quad][cg * 128 + nt * 16 + l15][0];
            accf[nt] = __builtin_amdgcn_mfma_f32_16x16x32_bf16(ax, bv, accf[nt], 0, 0, 0);
        }
    }

    // ---- ag GEMM: A = Pg (LDS-resident aggr_pre), B = WrT ----
    NF_LOADW(wrp, 0);
#pragma unroll 1
    for (int kk = 0; kk < C_; kk += 32) {
        BARRIER_LGKM();
        NF_STOREW();
        if (kk + 32 < C_) NF_LOADW(wrp, kk + 32);
        const bf16x8 ag = *(const bf16x8*)(const void*)
            &u.p2.Pg[(kk >> 3) + quad][rg * 16 + l15][0];
        BARRIER_LGKM();
#pragma unroll
        for (int nt = 0; nt < 8; ++nt) {
            const bf16x8 bv = *(const bf16x8*)(const void*)
                &u.p2.Bw[quad][cg * 128 + nt * 16 + l15][0];
            accg[nt] = __builtin_amdgcn_mfma_f32_16x16x32_bf16(ag, bv, accg[nt], 0, 0, 0);
        }
    }
#undef NF_LOADW
#undef NF_STOREW

    // ======================= epilogue =====================================
    const float bb = b_beta[i];
    const int rbase = rg * 16 + quad * 4;

    // pass 1: beta logit partials (this wave's 128 cols), cross-wave via LDS
#pragma unroll
    for (int reg = 0; reg < 4; ++reg) {
        float pb = 0.f;
#pragma unroll
        for (int nt = 0; nt < 8; ++nt) {
            const int c = cg * 128 + nt * 16 + l15;
            const float f = accf[nt][reg] + u.p2.prm[0][c];
            const float g = accg[nt][reg] + u.p2.prm[1][c];
            pb += f * u.p2.prm[2][c] + g * u.p2.prm[3][c];
        }
#pragma unroll
        for (int off = 1; off < 16; off <<= 1) pb += __shfl_xor(pb, off, 16);
        if (l15 == 0) u.p2.red[0][cg][rbase + reg] = pb;
    }
    __syncthreads();
    // pass 2: beta + LN stats
    float beta_r[4];
#pragma unroll
    for (int reg = 0; reg < 4; ++reg) {
        const int r = rbase + reg;
        const float logit = u.p2.red[0][0][r] + u.p2.red[0][1][r] + bb;
        const float beta = 1.f / (1.f + expf(-logit));
        beta_r[reg] = beta;
        float sh = 0.f, sh2 = 0.f;
#pragma unroll
        for (int nt = 0; nt < 8; ++nt) {
            const int c = cg * 128 + nt * 16 + l15;
            const float f = accf[nt][reg] + u.p2.prm[0][c];
            const float g = accg[nt][reg] + u.p2.prm[1][c];
            const float hh = g + (f - g) * beta;
            sh += hh; sh2 += hh * hh;
        }
#pragma unroll
        for (int off = 1; off < 16; off <<= 1) {
            sh  += __shfl_xor(sh,  off, 16);
            sh2 += __shfl_xor(sh2, off, 16);
        }
        if (l15 == 0) { u.p2.red[1][cg][r] = sh; u.p2.red[2][cg][r] = sh2; }
    }
    __syncthreads();
    // pass 3: normalize + relu + store
#pragma unroll
    for (int reg = 0; reg < 4; ++reg) {
        const int r = rbase + reg;
        const float sh  = u.p2.red[1][0][r] + u.p2.red[1][1][r];
        const float sh2 = u.p2.red[2][0][r] + u.p2.red[2][1][r];
        const float mu   = sh * (1.f / 256.f);
        const float var  = sh2 * (1.f / 256.f) - mu * mu;
        const float rstd = rsqrtf(var + 1e-5f);
        const float beta = beta_r[reg];
        float* op = out + ((size_t)(b * N_ + i * NLOC + R0 + r)) * C_;
#pragma unroll
        for (int nt = 0; nt < 8; ++nt) {
            const int c = cg * 128 + nt * 16 + l15;
            const float f = accf[nt][reg] + u.p2.prm[0][c];
            const float g = accg[nt][reg] + u.p2.prm[1][c];
            const float hh = g + (f - g) * beta;
            const float o = (hh - mu) * rstd * u.p2.prm[4][c] + u.p2.prm[5][c];
            op[c] = fmaxf(o, 0.f);
        }
    }
}

// ---------------------------------------------------------------------------
extern "C" void kernel_launch(void* const* d_in, const int* in_sizes, int n_in,
                              void* d_out, int out_size, void* d_ws, size_t ws_size,
                              hipStream_t stream) {
    const float* e       = (const float*)d_in[0];
    const float* x       = (const float*)d_in[1];
    // d_in[2] modal_id (int32): redundant (block structure is static)
    const float* W_feat  = (const float*)d_in[3];
    const float* b_feat  = (const float*)d_in[4];
    const float* W_raw   = (const float*)d_in[5];
    const float* b_raw   = (const float*)d_in[6];
    const float* W_beta  = (const float*)d_in[7];
    const float* b_beta  = (const float*)d_in[8];
    const float* ln_g    = (const float*)d_in[9];
    const float* ln_b    = (const float*)d_in[10];
    float* out = (float*)d_out;

    // workspace layout (bytes)
    char* ws = (char*)d_ws;
    bf16* xT  = (bf16*)(ws);                        // B*C*N*2 = 12,582,912
    bf16* WfT = (bf16*)(ws + 12582912);             // M*C*C*2 =    393,216
    bf16* WrT = (bf16*)(ws + 12582912 + 393216);    // M*C*C*2 =    393,216

    transpose_all_k<<<6528, dim3(32, 8), 0, stream>>>(x, W_feat, W_raw, xT, WfT, WrT);
    fused_k<<<dim3(NLOC / R_T, M_, B_), 256, 0, stream>>>(
        e, x, xT, WfT, WrT, b_feat, b_raw, W_beta, b_beta, ln_g, ln_b, out);
}

// Round 3
// 800.535 us; speedup vs baseline: 1.0418x; 1.0418x over previous
//
#include <hip/hip_runtime.h>
#include <cstdint>
#include <cstddef>

// Problem constants (B, N, C) = (4, 6144, 256), M = 3, n = 2048
#define B_   4
#define N_   6144
#define C_   256
#define M_   3
#define NLOC 2048
#define KH   1024   // split-K half of NLOC

static_assert(N_ == M_ * NLOC, "shape");
static_assert(2 * KH == NLOC, "splitk");

typedef __bf16 bf16;
typedef __bf16 bf16x8 __attribute__((ext_vector_type(8)));  // MFMA A/B operand (4 VGPRs)
typedef float  f32x4  __attribute__((ext_vector_type(4)));  // MFMA C/D operand / 16B chunk

// lgkm-only barrier: makes LDS writes visible WITHOUT draining outstanding
// global prefetch loads (__syncthreads() emits s_waitcnt vmcnt(0) which would
// serialize the software pipeline).
#define BARRIER_LGKM() asm volatile("s_waitcnt lgkmcnt(0)\n\ts_barrier" ::: "memory")

// ---------------------------------------------------------------------------
// One dispatch for all three transposes (x, W_feat, W_raw), fp32 -> bf16:
//   job 0: x  (B slices, N x C)  -> xT  (B, C, N)   blocks [0, 6144)
//   job 1: Wf (M slices, C x C)  -> WfT (M, C, C)   blocks [6144, 6336)
//   job 2: Wr (M slices, C x C)  -> WrT (M, C, C)   blocks [6336, 6528)
// ---------------------------------------------------------------------------
__global__ void transpose_all_k(const float* __restrict__ x,
                                const float* __restrict__ Wf,
                                const float* __restrict__ Wr,
                                bf16* __restrict__ xT,
                                bf16* __restrict__ WfT,
                                bf16* __restrict__ WrT) {
    const int id = blockIdx.x;
    const float* src;
    bf16* dst;
    int R, rb, cb;
    if (id < 6144) {                       // x: 4 slices x (192 rowblk x 8 colblk)
        const int s = id / 1536, r = id % 1536;
        rb = (r >> 3) * 32; cb = (r & 7) * 32;
        src = x  + (size_t)s * N_ * C_;
        dst = xT + (size_t)s * N_ * C_;
        R = N_;
    } else {                               // W: 2 mats x 3 slices x 64 blocks
        const int id2 = id - 6144;
        const int mat = id2 / 192, r = id2 % 192;
        const int s = r / 64, r2 = r % 64;
        rb = (r2 >> 3) * 32; cb = (r2 & 7) * 32;
        src = (mat ? Wr : Wf) + (size_t)s * C_ * C_;
        dst = (mat ? WrT : WfT) + (size_t)s * C_ * C_;
        R = C_;
    }
    __shared__ bf16 tile[32][33];
    const int tx = threadIdx.x, ty = threadIdx.y;  // 32 x 8
#pragma unroll
    for (int k = 0; k < 4; ++k)
        tile[ty + 8 * k][tx] = (bf16)src[(size_t)(rb + ty + 8 * k) * C_ + (cb + tx)];
    __syncthreads();
#pragma unroll
    for (int k = 0; k < 4; ++k)
        dst[(size_t)(cb + ty + 8 * k) * R + (rb + tx)] = tile[tx][ty + 8 * k];
}

// ---------------------------------------------------------------------------
// Kernel D (split-K): per (rowtile of 64, k-half, b*M+i) compute UNNORMALIZED
//   part[h][b][row][c] = sum_{j in half h} e_masked[row,j] * x[j,c]   (bf16)
//   rsg [h][b][row]    = sum_{j in half h} |bf16(e_masked[row,j])|    (fp32)
// Grid: (32, 2, 12) = 768 blocks = exactly 3 blocks/CU (even makespan).
// Two-phase reg-prefetch pipeline, double-buffered chunked LDS, one
// lgkm-only barrier per 32-k step. LDS layout [chunk][row][8] makes every
// 16-lane ds_read_b128 a contiguous 256B slab (conflict-free).
// ---------------------------------------------------------------------------
__global__ __launch_bounds__(256) void aggr_gemm_k(
    const float* __restrict__ e,    // (B, N, N) fp32
    const bf16*  __restrict__ xT,   // (B, C, N) bf16 ws
    bf16* __restrict__ part,        // (2, B, N, C) bf16 ws
    float* __restrict__ rsg)        // (2, B, N) fp32 ws
{
    __shared__ __align__(16) bf16 Abuf[2][4][64][8];   // [buf][k-chunk][row][8]
    __shared__ __align__(16) bf16 Bbuf[2][4][256][8];  // [buf][k-chunk][col][8]
    __shared__ float rsum[256];

    const int rt = blockIdx.x;            // row tile 0..31
    const int h  = blockIdx.y;            // k-half 0..1
    const int bi = blockIdx.z;            // b*M + i
    const int b  = bi / M_;
    const int i  = bi - b * M_;
    const int t = threadIdx.x;
    const int w = t >> 6, lane = t & 63, l15 = lane & 15, quad = lane >> 4;
    const int r_stage = t >> 2;           // 0..63: staged row
    const int chunk   = t & 3;            // k-chunk within BK=32
    const int ch8     = chunk * 8;

    // diagonal position of this staged row relative to this block's k-window
    const int dconst = rt * 64 + r_stage - h * KH - ch8;
    const float* eptr = e + ((size_t)(b * N_ + i * NLOC + rt * 64 + r_stage)) * N_
                          + i * NLOC + h * KH + ch8;
    const bf16* xTb = xT + (size_t)(b * C_) * N_ + i * NLOC + h * KH + ch8;

    f32x4 acc[4][4];
#pragma unroll
    for (int mt = 0; mt < 4; ++mt)
#pragma unroll
        for (int nt = 0; nt < 4; ++nt) { f32x4 z = {0.f, 0.f, 0.f, 0.f}; acc[mt][nt] = z; }

    float psum = 0.f;  // partial L1 row sum (this thread's k-chunks of its row)

    f32x4 ea0, ea1, xa0, xa1, xa2, xa3;   // prefetch register set A
    f32x4 eb0, eb1, xb0, xb1, xb2, xb3;   // prefetch register set B

#define AG_LOAD(E0, E1, X0, X1, X2, X3, KK)                                           \
    do {                                                                              \
        E0 = *(const f32x4*)(const void*)(eptr + (KK));                               \
        E1 = *(const f32x4*)(const void*)(eptr + (KK) + 4);                           \
        X0 = *(const f32x4*)(const void*)(xTb + (size_t)(r_stage)       * N_ + (KK)); \
        X1 = *(const f32x4*)(const void*)(xTb + (size_t)(r_stage +  64) * N_ + (KK)); \
        X2 = *(const f32x4*)(const void*)(xTb + (size_t)(r_stage + 128) * N_ + (KK)); \
        X3 = *(const f32x4*)(const void*)(xTb + (size_t)(r_stage + 192) * N_ + (KK)); \
    } while (0)

#define AG_STAGE(E0, E1, X0, X1, X2, X3, KK, BUF)                                     \
    do {                                                                              \
        const int d = dconst - (KK);                                                  \
        bf16x8 ab;                                                                    \
        _Pragma("unroll")                                                             \
        for (int j = 0; j < 8; ++j) {                                                 \
            float v = (j < 4) ? (E0)[j] : (E1)[j - 4];                                \
            v = (d == j) ? 0.f : v;   /* compile-time j: 8 cndmask, no scratch */     \
            const bf16 hh = (bf16)v;                                                  \
            ab[j] = hh;                                                               \
            psum += fabsf((float)hh);                                                 \
        }                                                                             \
        *(bf16x8*)(void*)&Abuf[BUF][chunk][r_stage][0] = ab;                          \
        *(f32x4*)(void*)&Bbuf[BUF][chunk][r_stage      ][0] = X0;                     \
        *(f32x4*)(void*)&Bbuf[BUF][chunk][r_stage +  64][0] = X1;                     \
        *(f32x4*)(void*)&Bbuf[BUF][chunk][r_stage + 128][0] = X2;                     \
        *(f32x4*)(void*)&Bbuf[BUF][chunk][r_stage + 192][0] = X3;                     \
    } while (0)

#define AG_COMPUTE(BUF)                                                               \
    do {                                                                              \
        bf16x8 af[4];                                                                 \
        _Pragma("unroll")                                                             \
        for (int mt = 0; mt < 4; ++mt)                                                \
            af[mt] = *(const bf16x8*)(const void*)&Abuf[BUF][quad][mt * 16 + l15][0]; \
        _Pragma("unroll")                                                             \
        for (int nt = 0; nt < 4; ++nt) {                                              \
            const bf16x8 bv = *(const bf16x8*)(const void*)                           \
                &Bbuf[BUF][quad][w * 64 + nt * 16 + l15][0];                          \
            _Pragma("unroll")                                                         \
            for (int mt = 0; mt < 4; ++mt)                                            \
                acc[mt][nt] = __builtin_amdgcn_mfma_f32_16x16x32_bf16(                \
                    af[mt], bv, acc[mt][nt], 0, 0, 0);                                \
        }                                                                             \
    } while (0)

    AG_LOAD(ea0, ea1, xa0, xa1, xa2, xa3, 0);
#pragma unroll 1
    for (int kk = 0; kk < KH; kk += 64) {
        AG_LOAD(eb0, eb1, xb0, xb1, xb2, xb3, kk + 32);     // in flight across barrier
        AG_STAGE(ea0, ea1, xa0, xa1, xa2, xa3, kk, 0);
        BARRIER_LGKM();
        if (kk + 64 < KH) AG_LOAD(ea0, ea1, xa0, xa1, xa2, xa3, kk + 64);  // 2 phases ahead
        AG_COMPUTE(0);
        AG_STAGE(eb0, eb1, xb0, xb1, xb2, xb3, kk + 32, 1);
        BARRIER_LGKM();
        AG_COMPUTE(1);
    }
#undef AG_LOAD
#undef AG_STAGE
#undef AG_COMPUTE

    // ---- reduce partial L1 sums: rsum[row*4 + chunk] ----
    rsum[t] = psum;
    __syncthreads();

    const size_t orow0 = (size_t)h * B_ * N_ + (size_t)b * N_ + i * NLOC + rt * 64;
    if (t < 64) {
        const float s = rsum[t * 4] + rsum[t * 4 + 1] + rsum[t * 4 + 2] + rsum[t * 4 + 3];
        rsg[orow0 + t] = s;
    }
    // ---- store UNNORMALIZED bf16 partial (normalization fused into node kernel) ----
#pragma unroll
    for (int mt = 0; mt < 4; ++mt) {
#pragma unroll
        for (int reg = 0; reg < 4; ++reg) {
            const int rr = mt * 16 + quad * 4 + reg;  // local row 0..63
            bf16* op = part + (orow0 + rr) * C_;
#pragma unroll
            for (int nt = 0; nt < 4; ++nt)
                op[w * 64 + nt * 16 + l15] = (bf16)acc[mt][nt][reg];
        }
    }
}

// ---------------------------------------------------------------------------
// Kernel E: per (b, modal, rowtile of 64):
//   aggr_pre = (part0+part1) / max(rsg0+rsg1, 1e-12)   (fused combine)
//   feat = x @ W_feat[i] + b_feat[i];  ag = aggr_pre @ W_raw[i] + b_raw[i]
//   beta = sigmoid(feat.(w1+w3) + ag.(w2-w3) + b_beta[i])
//   h = ag + (feat-ag)*beta;  out = relu(LN(h)*gamma + lbeta)
// Reg-prefetch + lgkm-only barriers (single LDS buffer, 2 barriers/iter),
// chunked conflict-free LDS layout.
// ---------------------------------------------------------------------------
__global__ __launch_bounds__(256) void node_final_k(
    const float* __restrict__ x,       // (B, N, C) fp32
    const bf16*  __restrict__ part,    // (2, B, N, C) bf16 ws
    const float* __restrict__ rsg,     // (2, B, N) fp32 ws
    const bf16* __restrict__ WfT,      // (M, C, C) bf16 ws, [out][k]
    const bf16* __restrict__ WrT,      // (M, C, C) bf16 ws
    const float* __restrict__ b_feat,  // (M, C) fp32
    const float* __restrict__ b_raw,   // (M, C) fp32
    const float* __restrict__ W_beta,  // (M, 3C) fp32
    const float* __restrict__ b_beta,  // (M,) fp32
    const float* __restrict__ ln_g,    // (M, C) fp32
    const float* __restrict__ ln_b,    // (M, C) fp32
    float* __restrict__ out)           // (B, N, C) fp32
{
    __shared__ __align__(16) bf16 Ax4[4][64][8], Ag4[4][64][8];
    __shared__ __align__(16) bf16 Bf4[4][256][8], Br4[4][256][8];
    __shared__ float pbf[256], pbr[256], pwA[256], pwB[256], pgm[256], plb[256];

    const int rt = blockIdx.x, i = blockIdx.y, b = blockIdx.z;
    const int t = threadIdx.x;
    const int w = t >> 6, lane = t & 63, l15 = lane & 15, quad = lane >> 4;
    const int r_stage = t >> 2, chunk = t & 3, ch8 = chunk * 8;

    // per-channel params -> LDS as fp32 (one channel per thread)
    {
        const int c = t;
        const float w3 = W_beta[i * 768 + 512 + c];
        pbf[c] = b_feat[i * C_ + c];
        pbr[c] = b_raw[i * C_ + c];
        pwA[c] = W_beta[i * 768 + c] + w3;
        pwB[c] = W_beta[i * 768 + 256 + c] - w3;
        pgm[c] = ln_g[i * C_ + c];
        plb[c] = ln_b[i * C_ + c];
    }

    f32x4 accf[16], accg[16];
#pragma unroll
    for (int nt = 0; nt < 16; ++nt) { f32x4 z = {0.f, 0.f, 0.f, 0.f}; accf[nt] = z; accg[nt] = z; }

    const size_t grow = (size_t)b * N_ + i * NLOC + rt * 64 + r_stage;
    const float ssum = rsg[grow] + rsg[(size_t)B_ * N_ + grow];
    const float inv_r = 1.f / fmaxf(ssum, 1e-12f);

    const float* xp = x    + grow * C_ + ch8;
    const bf16*  g0 = part + grow * C_ + ch8;
    const bf16*  g1 = g0 + (size_t)B_ * N_ * C_;
    const bf16* wf = WfT + (size_t)(i * C_) * C_ + ch8;
    const bf16* wr = WrT + (size_t)(i * C_) * C_ + ch8;

    f32x4 xv0, xv1;
    bf16x8 q0, q1;
    f32x4 wfv0, wfv1, wfv2, wfv3, wrv0, wrv1, wrv2, wrv3;

#define ND_LOAD(KK)                                                                    \
    do {                                                                               \
        xv0 = *(const f32x4*)(const void*)(xp + (KK));                                 \
        xv1 = *(const f32x4*)(const void*)(xp + (KK) + 4);                             \
        q0  = *(const bf16x8*)(const void*)(g0 + (KK));                                \
        q1  = *(const bf16x8*)(const void*)(g1 + (KK));                                \
        wfv0 = *(const f32x4*)(const void*)(wf + (size_t)(r_stage)       * C_ + (KK)); \
        wfv1 = *(const f32x4*)(const void*)(wf + (size_t)(r_stage +  64) * C_ + (KK)); \
        wfv2 = *(const f32x4*)(const void*)(wf + (size_t)(r_stage + 128) * C_ + (KK)); \
        wfv3 = *(const f32x4*)(const void*)(wf + (size_t)(r_stage + 192) * C_ + (KK)); \
        wrv0 = *(const f32x4*)(const void*)(wr + (size_t)(r_stage)       * C_ + (KK)); \
        wrv1 = *(const f32x4*)(const void*)(wr + (size_t)(r_stage +  64) * C_ + (KK)); \
        wrv2 = *(const f32x4*)(const void*)(wr + (size_t)(r_stage + 128) * C_ + (KK)); \
        wrv3 = *(const f32x4*)(const void*)(wr + (size_t)(r_stage + 192) * C_ + (KK)); \
    } while (0)

    ND_LOAD(0);
#pragma unroll 1
    for (int kk = 0; kk < C_; kk += 32) {
        BARRIER_LGKM();  // prior iteration's ds_reads drained (lgkm) + sync
        bf16x8 ax, ag;
#pragma unroll
        for (int j = 0; j < 4; ++j) {
            ax[j]     = (bf16)xv0[j];
            ax[j + 4] = (bf16)xv1[j];
        }
#pragma unroll
        for (int j = 0; j < 8; ++j)
            ag[j] = (bf16)(((float)q0[j] + (float)q1[j]) * inv_r);
        *(bf16x8*)(void*)&Ax4[chunk][r_stage][0] = ax;
        *(bf16x8*)(void*)&Ag4[chunk][r_stage][0] = ag;
        *(f32x4*)(void*)&Bf4[chunk][r_stage      ][0] = wfv0;
        *(f32x4*)(void*)&Bf4[chunk][r_stage +  64][0] = wfv1;
        *(f32x4*)(void*)&Bf4[chunk][r_stage + 128][0] = wfv2;
        *(f32x4*)(void*)&Bf4[chunk][r_stage + 192][0] = wfv3;
        *(f32x4*)(void*)&Br4[chunk][r_stage      ][0] = wrv0;
        *(f32x4*)(void*)&Br4[chunk][r_stage +  64][0] = wrv1;
        *(f32x4*)(void*)&Br4[chunk][r_stage + 128][0] = wrv2;
        *(f32x4*)(void*)&Br4[chunk][r_stage + 192][0] = wrv3;
        if (kk + 32 < C_) ND_LOAD(kk + 32);  // next tile in flight under compute
        BARRIER_LGKM();  // staged writes visible; prefetch NOT drained
        const bf16x8 axf = *(const bf16x8*)(const void*)&Ax4[quad][w * 16 + l15][0];
        const bf16x8 agf = *(const bf16x8*)(const void*)&Ag4[quad][w * 16 + l15][0];
#pragma unroll
        for (int nt = 0; nt < 16; ++nt) {
            const bf16x8 bfv = *(const bf16x8*)(const void*)&Bf4[quad][nt * 16 + l15][0];
            const bf16x8 brv = *(const bf16x8*)(const void*)&Br4[quad][nt * 16 + l15][0];
            accf[nt] = __builtin_amdgcn_mfma_f32_16x16x32_bf16(axf, bfv, accf[nt], 0, 0, 0);
            accg[nt] = __builtin_amdgcn_mfma_f32_16x16x32_bf16(agf, brv, accg[nt], 0, 0, 0);
        }
    }
#undef ND_LOAD

    const float bb = b_beta[i];
    const int rowbase = i * NLOC + rt * 64 + w * 16 + quad * 4;
#pragma unroll
    for (int reg = 0; reg < 4; ++reg) {
        // pass 1: beta logit
        float pb = 0.f;
#pragma unroll
        for (int nt = 0; nt < 16; ++nt) {
            const int c = nt * 16 + l15;
            const float f = accf[nt][reg] + pbf[c];
            const float g = accg[nt][reg] + pbr[c];
            pb += f * pwA[c] + g * pwB[c];
        }
#pragma unroll
        for (int off = 1; off < 16; off <<= 1) pb += __shfl_xor(pb, off, 16);
        const float beta = 1.f / (1.f + expf(-(pb + bb)));
        // pass 2: LN statistics
        float sh = 0.f, sh2 = 0.f;
#pragma unroll
        for (int nt = 0; nt < 16; ++nt) {
            const int c = nt * 16 + l15;
            const float f = accf[nt][reg] + pbf[c];
            const float g = accg[nt][reg] + pbr[c];
            const float hh = g + (f - g) * beta;
            sh += hh; sh2 += hh * hh;
        }
#pragma unroll
        for (int off = 1; off < 16; off <<= 1) {
            sh  += __shfl_xor(sh,  off, 16);
            sh2 += __shfl_xor(sh2, off, 16);
        }
        const float mu   = sh * (1.f / 256.f);
        const float var  = sh2 * (1.f / 256.f) - mu * mu;
        const float rstd = rsqrtf(var + 1e-5f);
        // pass 3: normalize + relu + store (fp32)
        float* op = out + (size_t)(b * N_ + rowbase + reg) * C_;
#pragma unroll
        for (int nt = 0; nt < 16; ++nt) {
            const int c = nt * 16 + l15;
            const float f = accf[nt][reg] + pbf[c];
            const float g = accg[nt][reg] + pbr[c];
            const float hh = g + (f - g) * beta;
            const float o = (hh - mu) * rstd * pgm[c] + plb[c];
            op[c] = fmaxf(o, 0.f);
        }
    }
}

// ---------------------------------------------------------------------------
extern "C" void kernel_launch(void* const* d_in, const int* in_sizes, int n_in,
                              void* d_out, int out_size, void* d_ws, size_t ws_size,
                              hipStream_t stream) {
    const float* e       = (const float*)d_in[0];
    const float* x       = (const float*)d_in[1];
    // d_in[2] modal_id (int32): redundant (block structure is static)
    const float* W_feat  = (const float*)d_in[3];
    const float* b_feat  = (const float*)d_in[4];
    const float* W_raw   = (const float*)d_in[5];
    const float* b_raw   = (const float*)d_in[6];
    const float* W_beta  = (const float*)d_in[7];
    const float* b_beta  = (const float*)d_in[8];
    const float* ln_g    = (const float*)d_in[9];
    const float* ln_b    = (const float*)d_in[10];
    float* out = (float*)d_out;

    // workspace layout (bytes)
    char* ws = (char*)d_ws;
    bf16*  xT   = (bf16*)(ws);                            // B*C*N*2   = 12,582,912
    bf16*  WfT  = (bf16*)(ws + 12582912);                 // M*C*C*2   =    393,216
    bf16*  WrT  = (bf16*)(ws + 12582912 + 393216);        // M*C*C*2   =    393,216
    bf16*  part = (bf16*)(ws + 13369344);                 // 2*B*N*C*2 = 25,165,824
    float* rsg  = (float*)(ws + 13369344 + 25165824);     // 2*B*N*4   =    196,608
                                                          // total 38,731,776 B

    transpose_all_k<<<6528, dim3(32, 8), 0, stream>>>(x, W_feat, W_raw, xT, WfT, WrT);
    aggr_gemm_k<<<dim3(NLOC / 64, 2, B_ * M_), 256, 0, stream>>>(e, xT, part, rsg);
    node_final_k<<<dim3(NLOC / 64, M_, B_), 256, 0, stream>>>(
        x, part, rsg, WfT, WrT, b_feat, b_raw, W_beta, b_beta, ln_g, ln_b, out);
}